// Round 1
// baseline (177.378 us; speedup 1.0000x reference)
//
#include <hip/hip_runtime.h>
#include <hip/hip_bf16.h>

#define NHEAD 8
#define KSZ 7
#define HDIM 32
#define HS 56
#define WS 56

// ---------------------------------------------------------------------------
// Generic fp32 GEMM: C[M,N] = (A[M,K] @ B[K,N] + bias[N]) * scale
// BM=BN=64, BK=16, 256 threads, 4x4 per thread. M%64==0, N%64==0, K%16==0.
// ---------------------------------------------------------------------------
template<int BM, int BN, int BK>
__global__ __launch_bounds__(256) void gemm_bias_kernel(
    const float* __restrict__ A, const float* __restrict__ B,
    const float* __restrict__ bias, float* __restrict__ C,
    int M, int N, int K, float scale)
{
    __shared__ float As[BK][BM + 4];   // transposed A tile, +4 pad (keeps 16B align, spreads banks)
    __shared__ float Bs[BK][BN + 4];

    const int tid = threadIdx.x;
    const int tx = tid & 15;          // output col group
    const int ty = tid >> 4;          // output row group
    const int m0 = blockIdx.y * BM;
    const int n0 = blockIdx.x * BN;

    // A tile load: thread -> row tid/4 (0..63), cols (tid&3)*4 .. +3
    const int arow = tid >> 2;
    const int acol = (tid & 3) * 4;
    // B tile load: thread -> row tid/16 (0..15), cols (tid&15)*4 .. +3
    const int brow = tid >> 4;
    const int bcol = (tid & 15) * 4;

    float acc[4][4];
    #pragma unroll
    for (int i = 0; i < 4; ++i)
        #pragma unroll
        for (int j = 0; j < 4; ++j) acc[i][j] = 0.f;

    for (int k0 = 0; k0 < K; k0 += BK) {
        float4 av = *reinterpret_cast<const float4*>(&A[(size_t)(m0 + arow) * K + k0 + acol]);
        float4 bv = *reinterpret_cast<const float4*>(&B[(size_t)(k0 + brow) * N + n0 + bcol]);
        __syncthreads();   // previous iteration's reads complete before overwrite
        As[acol + 0][arow] = av.x;
        As[acol + 1][arow] = av.y;
        As[acol + 2][arow] = av.z;
        As[acol + 3][arow] = av.w;
        *reinterpret_cast<float4*>(&Bs[brow][bcol]) = bv;
        __syncthreads();

        #pragma unroll
        for (int kk = 0; kk < BK; ++kk) {
            float4 a = *reinterpret_cast<const float4*>(&As[kk][ty * 4]);
            float4 b = *reinterpret_cast<const float4*>(&Bs[kk][tx * 4]);
            const float ar[4] = {a.x, a.y, a.z, a.w};
            const float br[4] = {b.x, b.y, b.z, b.w};
            #pragma unroll
            for (int i = 0; i < 4; ++i)
                #pragma unroll
                for (int j = 0; j < 4; ++j)
                    acc[i][j] = fmaf(ar[i], br[j], acc[i][j]);
        }
    }

    #pragma unroll
    for (int i = 0; i < 4; ++i) {
        float4 o;
        o.x = (acc[i][0] + bias[n0 + tx * 4 + 0]) * scale;
        o.y = (acc[i][1] + bias[n0 + tx * 4 + 1]) * scale;
        o.z = (acc[i][2] + bias[n0 + tx * 4 + 2]) * scale;
        o.w = (acc[i][3] + bias[n0 + tx * 4 + 3]) * scale;
        *reinterpret_cast<float4*>(&C[(size_t)(m0 + ty * 4 + i) * N + n0 + tx * 4]) = o;
    }
}

// ---------------------------------------------------------------------------
// Neighborhood attention: one thread per (b, head, i, j).
// qb:  [B*H*W, 256]  (already scaled by hd^-0.5), channel = n*32+d
// kvb: [B*H*W, 512]  cols 0..255 = K (n*32+d), cols 256..511 = V
// rpb: [8,13,13]
// ob:  [B*H*W, 256]
// ---------------------------------------------------------------------------
__global__ __launch_bounds__(256) void natten_kernel(
    const float* __restrict__ qb, const float* __restrict__ kvb,
    const float* __restrict__ rpb, float* __restrict__ ob)
{
    const int t = blockIdx.x * 256 + threadIdx.x;
    const int n = t & 7;
    const int tok = t >> 3;
    const int j = tok % WS;
    const int i = (tok / WS) % HS;

    int si = i - 3; si = si < 0 ? 0 : si; si = si > HS - KSZ ? HS - KSZ : si;
    int sj = j - 3; sj = sj < 0 ? 0 : sj; sj = sj > WS - KSZ ? WS - KSZ : sj;

    const int base = tok + (si - i) * WS + (sj - j);             // token of neighbor (0,0)
    const float* rp = rpb + n * 169 + (si - i + 6) * 13 + (sj - j + 6);

    float4 q[8];
    const float4* qp = reinterpret_cast<const float4*>(qb + (size_t)tok * 256 + n * 32);
    #pragma unroll
    for (int d = 0; d < 8; ++d) q[d] = qp[d];

    float logits[49];
    #pragma unroll
    for (int ki = 0; ki < KSZ; ++ki) {
        #pragma unroll
        for (int kj = 0; kj < KSZ; ++kj) {
            const float4* kp = reinterpret_cast<const float4*>(
                kvb + (size_t)(base + ki * WS + kj) * 512 + n * 32);
            float s0 = 0.f, s1 = 0.f, s2 = 0.f, s3 = 0.f;
            #pragma unroll
            for (int d = 0; d < 8; ++d) {
                float4 kv = kp[d];
                s0 = fmaf(q[d].x, kv.x, s0);
                s1 = fmaf(q[d].y, kv.y, s1);
                s2 = fmaf(q[d].z, kv.z, s2);
                s3 = fmaf(q[d].w, kv.w, s3);
            }
            logits[ki * 7 + kj] = (s0 + s1) + (s2 + s3) + rp[ki * 13 + kj];
        }
    }

    float m = -1e30f;
    #pragma unroll
    for (int l = 0; l < 49; ++l) m = fmaxf(m, logits[l]);
    float ssum = 0.f;
    #pragma unroll
    for (int l = 0; l < 49; ++l) {
        float e = __expf(logits[l] - m);
        logits[l] = e;
        ssum += e;
    }

    float4 acc[8];
    #pragma unroll
    for (int d = 0; d < 8; ++d) acc[d] = make_float4(0.f, 0.f, 0.f, 0.f);

    #pragma unroll
    for (int ki = 0; ki < KSZ; ++ki) {
        #pragma unroll
        for (int kj = 0; kj < KSZ; ++kj) {
            const float w = logits[ki * 7 + kj];
            const float4* vp = reinterpret_cast<const float4*>(
                kvb + (size_t)(base + ki * WS + kj) * 512 + 256 + n * 32);
            #pragma unroll
            for (int d = 0; d < 8; ++d) {
                float4 vv = vp[d];
                acc[d].x = fmaf(w, vv.x, acc[d].x);
                acc[d].y = fmaf(w, vv.y, acc[d].y);
                acc[d].z = fmaf(w, vv.z, acc[d].z);
                acc[d].w = fmaf(w, vv.w, acc[d].w);
            }
        }
    }

    const float inv = 1.f / ssum;
    float4* op = reinterpret_cast<float4*>(ob + (size_t)tok * 256 + n * 32);
    #pragma unroll
    for (int d = 0; d < 8; ++d) {
        acc[d].x *= inv; acc[d].y *= inv; acc[d].z *= inv; acc[d].w *= inv;
        op[d] = acc[d];
    }
}

// ---------------------------------------------------------------------------
extern "C" void kernel_launch(void* const* d_in, const int* in_sizes, int n_in,
                              void* d_out, int out_size, void* d_ws, size_t ws_size,
                              hipStream_t stream) {
    const float* x_q   = (const float*)d_in[0];
    const float* x_k   = (const float*)d_in[1];
    const float* Wq    = (const float*)d_in[2];
    const float* bq    = (const float*)d_in[3];
    const float* Wkv   = (const float*)d_in[4];
    const float* bkv   = (const float*)d_in[5];
    const float* rpb   = (const float*)d_in[6];
    const float* Wproj = (const float*)d_in[7];
    const float* bproj = (const float*)d_in[8];
    float* out = (float*)d_out;

    const int M = 2 * HS * WS;        // 6272 tokens
    float* qbuf  = (float*)d_ws;                    // M*256 floats
    float* kvbuf = qbuf + (size_t)M * 256;          // M*512 floats
    float* attbuf = kvbuf + (size_t)M * 512;        // M*256 floats

    const float scale = 0.17677669529663687f;       // 32^-0.5

    dim3 blk(256);
    // q projection (scaled)
    gemm_bias_kernel<64, 64, 16><<<dim3(256 / 64, M / 64), blk, 0, stream>>>(
        x_q, Wq, bq, qbuf, M, 256, 256, scale);
    // kv projection
    gemm_bias_kernel<64, 64, 16><<<dim3(512 / 64, M / 64), blk, 0, stream>>>(
        x_k, Wkv, bkv, kvbuf, M, 512, 256, 1.0f);
    // neighborhood attention
    natten_kernel<<<dim3(M * NHEAD / 256), blk, 0, stream>>>(qbuf, kvbuf, rpb, attbuf);
    // output projection
    gemm_bias_kernel<64, 64, 16><<<dim3(256 / 64, M / 64), blk, 0, stream>>>(
        attbuf, Wproj, bproj, out, M, 256, 256, 1.0f);
}

// Round 2
// 140.730 us; speedup vs baseline: 1.2604x; 1.2604x over previous
//
#include <hip/hip_runtime.h>
#include <hip/hip_bf16.h>

#define NHEAD 8
#define KSZ 7
#define HDIM 32
#define HS 56
#define WS 56

// ---------------------------------------------------------------------------
// fp32 GEMM: C[M,N] = (A[M,K] @ B[K,N] + bias[N]) * scale
// BM=128, BN=64, BK=16, 256 threads, 8x4 per thread. M%128==0, N%64==0, K%16==0.
// ---------------------------------------------------------------------------
template<int BM, int BN, int BK>
__global__ __launch_bounds__(256) void gemm_bias_kernel(
    const float* __restrict__ A, const float* __restrict__ B,
    const float* __restrict__ bias, float* __restrict__ C,
    int M, int N, int K, float scale)
{
    __shared__ float As[BK][BM + 4];   // transposed A tile
    __shared__ float Bs[BK][BN + 4];

    const int tid = threadIdx.x;
    const int tx = tid & 15;          // output col group (4 cols)
    const int ty = tid >> 4;          // output row group (8 rows)
    const int m0 = blockIdx.y * BM;
    const int n0 = blockIdx.x * BN;

    // A tile load: thread -> row tid/2 (0..127), cols (tid&1)*8 .. +7 (two float4)
    const int arow = tid >> 1;
    const int acol = (tid & 1) * 8;
    // B tile load: thread -> row tid/16 (0..15), cols (tid&15)*4 .. +3
    const int brow = tid >> 4;
    const int bcol = (tid & 15) * 4;

    float acc[8][4];
    #pragma unroll
    for (int i = 0; i < 8; ++i)
        #pragma unroll
        for (int j = 0; j < 4; ++j) acc[i][j] = 0.f;

    for (int k0 = 0; k0 < K; k0 += BK) {
        float4 av0 = *reinterpret_cast<const float4*>(&A[(size_t)(m0 + arow) * K + k0 + acol]);
        float4 av1 = *reinterpret_cast<const float4*>(&A[(size_t)(m0 + arow) * K + k0 + acol + 4]);
        float4 bv  = *reinterpret_cast<const float4*>(&B[(size_t)(k0 + brow) * N + n0 + bcol]);
        __syncthreads();   // previous iteration's reads complete before overwrite
        As[acol + 0][arow] = av0.x;
        As[acol + 1][arow] = av0.y;
        As[acol + 2][arow] = av0.z;
        As[acol + 3][arow] = av0.w;
        As[acol + 4][arow] = av1.x;
        As[acol + 5][arow] = av1.y;
        As[acol + 6][arow] = av1.z;
        As[acol + 7][arow] = av1.w;
        *reinterpret_cast<float4*>(&Bs[brow][bcol]) = bv;
        __syncthreads();

        #pragma unroll
        for (int kk = 0; kk < BK; ++kk) {
            float4 a0 = *reinterpret_cast<const float4*>(&As[kk][ty * 8]);
            float4 a1 = *reinterpret_cast<const float4*>(&As[kk][ty * 8 + 4]);
            float4 b  = *reinterpret_cast<const float4*>(&Bs[kk][tx * 4]);
            const float ar[8] = {a0.x, a0.y, a0.z, a0.w, a1.x, a1.y, a1.z, a1.w};
            const float br[4] = {b.x, b.y, b.z, b.w};
            #pragma unroll
            for (int i = 0; i < 8; ++i)
                #pragma unroll
                for (int j = 0; j < 4; ++j)
                    acc[i][j] = fmaf(ar[i], br[j], acc[i][j]);
        }
    }

    const float bb[4] = {bias[n0 + tx * 4 + 0], bias[n0 + tx * 4 + 1],
                         bias[n0 + tx * 4 + 2], bias[n0 + tx * 4 + 3]};
    #pragma unroll
    for (int i = 0; i < 8; ++i) {
        float4 o;
        o.x = (acc[i][0] + bb[0]) * scale;
        o.y = (acc[i][1] + bb[1]) * scale;
        o.z = (acc[i][2] + bb[2]) * scale;
        o.w = (acc[i][3] + bb[3]) * scale;
        *reinterpret_cast<float4*>(&C[(size_t)(m0 + ty * 8 + i) * N + n0 + tx * 4]) = o;
    }
}

// ---------------------------------------------------------------------------
// Neighborhood attention, wave-per-token.
// Lane l (0..63): head = l>>3, dim group dg = l&7 (floats dg*4 .. dg*4+3).
// A wave's 64 lanes cover one full 256-channel row -> every K/V/q/out access
// is one contiguous 1KB transaction.
// QK^T: per-lane 4-element partial dot, reduced over the 8 lanes of a head
// via shfl_xor(1,2,4); every lane keeps all 49 logits and does softmax
// redundantly; PV accumulates 4 dims per lane.
// Grid is XCD-swizzled: 1568 blocks = 8 XCDs x 196 contiguous blocks, so each
// XCD's L2 sees a ~2.2MB contiguous image slab instead of the whole 12.8MB.
// ---------------------------------------------------------------------------
__global__ __launch_bounds__(256) void natten_kernel(
    const float* __restrict__ qb, const float* __restrict__ kvb,
    const float* __restrict__ rpb, float* __restrict__ ob)
{
    const int nwg = gridDim.x;                 // 1568, divisible by 8
    const int bid = blockIdx.x;
    const int swz = (bid & 7) * (nwg >> 3) + (bid >> 3);   // XCD-contiguous

    const int lane = threadIdx.x & 63;
    const int tok  = swz * 4 + (threadIdx.x >> 6);
    const int head = lane >> 3;

    const int j = tok % WS;
    const int i = (tok / WS) % HS;

    int si = i - 3; si = si < 0 ? 0 : si; si = si > HS - KSZ ? HS - KSZ : si;
    int sj = j - 3; sj = sj < 0 ? 0 : sj; sj = sj > WS - KSZ ? WS - KSZ : sj;

    const int base = tok + (si - i) * WS + (sj - j);   // token of neighbor (0,0)
    const float* rp = rpb + head * 169 + (si - i + 6) * 13 + (sj - j + 6);

    const float4 q = *reinterpret_cast<const float4*>(qb + (size_t)tok * 256 + lane * 4);

    float logits[49];
    #pragma unroll
    for (int ki = 0; ki < KSZ; ++ki) {
        #pragma unroll
        for (int kj = 0; kj < KSZ; ++kj) {
            const float4 k = *reinterpret_cast<const float4*>(
                kvb + (size_t)(base + ki * WS + kj) * 512 + lane * 4);
            float p = q.x * k.x;
            p = fmaf(q.y, k.y, p);
            p = fmaf(q.z, k.z, p);
            p = fmaf(q.w, k.w, p);
            p += __shfl_xor(p, 1);
            p += __shfl_xor(p, 2);
            p += __shfl_xor(p, 4);
            logits[ki * 7 + kj] = p + rp[ki * 13 + kj];
        }
    }

    float m = -1e30f;
    #pragma unroll
    for (int l = 0; l < 49; ++l) m = fmaxf(m, logits[l]);
    float ssum = 0.f;
    #pragma unroll
    for (int l = 0; l < 49; ++l) {
        float e = __expf(logits[l] - m);
        logits[l] = e;
        ssum += e;
    }

    float4 acc = make_float4(0.f, 0.f, 0.f, 0.f);
    #pragma unroll
    for (int ki = 0; ki < KSZ; ++ki) {
        #pragma unroll
        for (int kj = 0; kj < KSZ; ++kj) {
            const float w = logits[ki * 7 + kj];
            const float4 v = *reinterpret_cast<const float4*>(
                kvb + (size_t)(base + ki * WS + kj) * 512 + 256 + lane * 4);
            acc.x = fmaf(w, v.x, acc.x);
            acc.y = fmaf(w, v.y, acc.y);
            acc.z = fmaf(w, v.z, acc.z);
            acc.w = fmaf(w, v.w, acc.w);
        }
    }

    const float inv = 1.f / ssum;
    acc.x *= inv; acc.y *= inv; acc.z *= inv; acc.w *= inv;
    *reinterpret_cast<float4*>(ob + (size_t)tok * 256 + lane * 4) = acc;
}

// ---------------------------------------------------------------------------
extern "C" void kernel_launch(void* const* d_in, const int* in_sizes, int n_in,
                              void* d_out, int out_size, void* d_ws, size_t ws_size,
                              hipStream_t stream) {
    const float* x_q   = (const float*)d_in[0];
    const float* x_k   = (const float*)d_in[1];
    const float* Wq    = (const float*)d_in[2];
    const float* bq    = (const float*)d_in[3];
    const float* Wkv   = (const float*)d_in[4];
    const float* bkv   = (const float*)d_in[5];
    const float* rpb   = (const float*)d_in[6];
    const float* Wproj = (const float*)d_in[7];
    const float* bproj = (const float*)d_in[8];
    float* out = (float*)d_out;

    const int M = 2 * HS * WS;        // 6272 tokens
    float* qbuf   = (float*)d_ws;                   // M*256 floats
    float* kvbuf  = qbuf + (size_t)M * 256;         // M*512 floats
    float* attbuf = kvbuf + (size_t)M * 512;        // M*256 floats

    const float scale = 0.17677669529663687f;       // 32^-0.5

    dim3 blk(256);
    // q projection (scaled)
    gemm_bias_kernel<128, 64, 16><<<dim3(256 / 64, M / 128), blk, 0, stream>>>(
        x_q, Wq, bq, qbuf, M, 256, 256, scale);
    // kv projection
    gemm_bias_kernel<128, 64, 16><<<dim3(512 / 64, M / 128), blk, 0, stream>>>(
        x_k, Wkv, bkv, kvbuf, M, 512, 256, 1.0f);
    // neighborhood attention: wave per token, 4 toks per block
    natten_kernel<<<dim3(M / 4), blk, 0, stream>>>(qbuf, kvbuf, rpb, attbuf);
    // output projection
    gemm_bias_kernel<128, 64, 16><<<dim3(256 / 64, M / 128), blk, 0, stream>>>(
        attbuf, Wproj, bproj, out, M, 256, 256, 1.0f);
}

// Round 3
// 99.911 us; speedup vs baseline: 1.7754x; 1.4086x over previous
//
#include <hip/hip_runtime.h>
#include <hip/hip_bf16.h>

#define NHEAD 8
#define KSZ 7
#define HS 56
#define WS 56

// ---------------------------------------------------------------------------
// fp32 GEMM: C[M,N] = (A[M,K] @ B[K,N] + bias[N]) * scale
// BM=BN=64, BK=16, 256 threads, 4x4 per thread.
// ---------------------------------------------------------------------------
template<int BM, int BN, int BK>
__global__ __launch_bounds__(256) void gemm_bias_kernel(
    const float* __restrict__ A, const float* __restrict__ B,
    const float* __restrict__ bias, float* __restrict__ C,
    int M, int N, int K, float scale)
{
    __shared__ float As[BK][BM + 4];
    __shared__ float Bs[BK][BN + 4];

    const int tid = threadIdx.x;
    const int tx = tid & 15;
    const int ty = tid >> 4;
    const int m0 = blockIdx.y * BM;
    const int n0 = blockIdx.x * BN;

    const int arow = tid >> 2;
    const int acol = (tid & 3) * 4;
    const int brow = tid >> 4;
    const int bcol = (tid & 15) * 4;

    float acc[4][4];
    #pragma unroll
    for (int i = 0; i < 4; ++i)
        #pragma unroll
        for (int j = 0; j < 4; ++j) acc[i][j] = 0.f;

    for (int k0 = 0; k0 < K; k0 += BK) {
        float4 av = *reinterpret_cast<const float4*>(&A[(size_t)(m0 + arow) * K + k0 + acol]);
        float4 bv = *reinterpret_cast<const float4*>(&B[(size_t)(k0 + brow) * N + n0 + bcol]);
        __syncthreads();
        As[acol + 0][arow] = av.x;
        As[acol + 1][arow] = av.y;
        As[acol + 2][arow] = av.z;
        As[acol + 3][arow] = av.w;
        *reinterpret_cast<float4*>(&Bs[brow][bcol]) = bv;
        __syncthreads();

        #pragma unroll
        for (int kk = 0; kk < BK; ++kk) {
            float4 a = *reinterpret_cast<const float4*>(&As[kk][ty * 4]);
            float4 b = *reinterpret_cast<const float4*>(&Bs[kk][tx * 4]);
            const float ar[4] = {a.x, a.y, a.z, a.w};
            const float br[4] = {b.x, b.y, b.z, b.w};
            #pragma unroll
            for (int i = 0; i < 4; ++i)
                #pragma unroll
                for (int j = 0; j < 4; ++j)
                    acc[i][j] = fmaf(ar[i], br[j], acc[i][j]);
        }
    }

    #pragma unroll
    for (int i = 0; i < 4; ++i) {
        float4 o;
        o.x = (acc[i][0] + bias[n0 + tx * 4 + 0]) * scale;
        o.y = (acc[i][1] + bias[n0 + tx * 4 + 1]) * scale;
        o.z = (acc[i][2] + bias[n0 + tx * 4 + 2]) * scale;
        o.w = (acc[i][3] + bias[n0 + tx * 4 + 3]) * scale;
        *reinterpret_cast<float4*>(&C[(size_t)(m0 + ty * 4 + i) * N + n0 + tx * 4]) = o;
    }
}

// ---------------------------------------------------------------------------
// LDS-tiled neighborhood attention.
// Block = (batch, head, 8x8 token tile). 256 threads = 64 tokens x 4 quarters.
// Thread (tok, q4) owns dims q4*8 .. q4*8+7 of its token's 32-dim head slice.
// Stage the 14x14 halo region's K rows ([196][32] f32, stride 36 dwords for
// bank spread, ~28KB) in LDS, compute QK from LDS, then REUSE the same buffer
// for V (barrier-separated phases). Only 2 shuffles per logit (4-lane reduce).
// Swizzle: head = bid&7 -> all blocks of one head land on one XCD; that
// head's K/V slice is 1.6MB and fits the 4MB XCD L2.
// ---------------------------------------------------------------------------
#define REG 14           // halo region edge (8 + 6)
#define NREG (REG*REG)   // 196
#define KST 36           // LDS row stride in dwords (32 data + 4 pad)

__global__ __launch_bounds__(256) void natten_kernel(
    const float* __restrict__ qb, const float* __restrict__ kvb,
    const float* __restrict__ rpb, float* __restrict__ ob)
{
    __shared__ float Ks[NREG * KST];   // K region, then reused for V
    __shared__ float Rp[169];

    const int tid = threadIdx.x;
    const int bid = blockIdx.x;             // 784 blocks
    const int head = bid & 7;               // XCD-local head
    const int idx  = bid >> 3;              // 0..97
    const int b    = idx / 49;
    const int t49  = idx % 49;
    const int ti0  = (t49 / 7) * 8;
    const int tj0  = (t49 % 7) * 8;

    // region origin (always 14x14 window covering all token windows in tile)
    int gr0 = ti0 - 3; gr0 = gr0 < 0 ? 0 : gr0; gr0 = gr0 > HS - REG ? HS - REG : gr0;
    int gc0 = tj0 - 3; gc0 = gc0 < 0 ? 0 : gc0; gc0 = gc0 > WS - REG ? WS - REG : gc0;

    const float* kvb_head = kvb + (size_t)b * 3136 * 512 + head * 32;

    // ---- stage K ----
    #pragma unroll
    for (int rt0 = 0; rt0 < NREG; rt0 += 32) {
        const int rt = rt0 + (tid >> 3);
        if (rt < NREG) {
            const int r = rt / REG, c = rt % REG;
            const int g = (gr0 + r) * WS + (gc0 + c);
            const float4 v = *reinterpret_cast<const float4*>(
                kvb_head + (size_t)g * 512 + (tid & 7) * 4);
            *reinterpret_cast<float4*>(&Ks[rt * KST + (tid & 7) * 4]) = v;
        }
    }
    if (tid < 169) Rp[tid] = rpb[head * 169 + tid];

    // ---- per-thread token / quarter ----
    const int tokl = tid >> 2;          // 0..63
    const int q4   = tid & 3;           // dim quarter
    const int tr = tokl >> 3, tc = tokl & 7;
    const int i = ti0 + tr, j = tj0 + tc;

    int si = i - 3; si = si < 0 ? 0 : si; si = si > HS - KSZ ? HS - KSZ : si;
    int sj = j - 3; sj = sj < 0 ? 0 : sj; sj = sj > WS - KSZ ? WS - KSZ : sj;

    const int nb0 = (si - gr0) * REG + (sj - gc0);      // region index of nb(0,0)
    const int rb0 = (si - i + 6) * 13 + (sj - j + 6);   // rpb index of nb(0,0)
    const int tokflat = b * 3136 + i * WS + j;

    const float* qp = qb + (size_t)tokflat * 256 + head * 32 + q4 * 8;
    const float4 qv0 = *reinterpret_cast<const float4*>(qp);
    const float4 qv1 = *reinterpret_cast<const float4*>(qp + 4);

    __syncthreads();

    // ---- QK^T + bias ----
    float lg[49];
    #pragma unroll
    for (int ki = 0; ki < KSZ; ++ki) {
        #pragma unroll
        for (int kj = 0; kj < KSZ; ++kj) {
            const float* kp = &Ks[(nb0 + ki * REG + kj) * KST + q4 * 8];
            const float4 k0 = *reinterpret_cast<const float4*>(kp);
            const float4 k1 = *reinterpret_cast<const float4*>(kp + 4);
            float p = qv0.x * k0.x;
            p = fmaf(qv0.y, k0.y, p);
            p = fmaf(qv0.z, k0.z, p);
            p = fmaf(qv0.w, k0.w, p);
            p = fmaf(qv1.x, k1.x, p);
            p = fmaf(qv1.y, k1.y, p);
            p = fmaf(qv1.z, k1.z, p);
            p = fmaf(qv1.w, k1.w, p);
            p += __shfl_xor(p, 1);
            p += __shfl_xor(p, 2);
            lg[ki * 7 + kj] = p + Rp[rb0 + ki * 13 + kj];
        }
    }

    // ---- softmax (register-only, redundant across the 4 quarter-lanes) ----
    float m = -1e30f;
    #pragma unroll
    for (int l = 0; l < 49; ++l) m = fmaxf(m, lg[l]);
    float ssum = 0.f;
    #pragma unroll
    for (int l = 0; l < 49; ++l) {
        const float e = __expf(lg[l] - m);
        lg[l] = e;
        ssum += e;
    }

    __syncthreads();   // all K reads done before V overwrites

    // ---- stage V (same buffer) ----
    #pragma unroll
    for (int rt0 = 0; rt0 < NREG; rt0 += 32) {
        const int rt = rt0 + (tid >> 3);
        if (rt < NREG) {
            const int r = rt / REG, c = rt % REG;
            const int g = (gr0 + r) * WS + (gc0 + c);
            const float4 v = *reinterpret_cast<const float4*>(
                kvb_head + (size_t)g * 512 + 256 + (tid & 7) * 4);
            *reinterpret_cast<float4*>(&Ks[rt * KST + (tid & 7) * 4]) = v;
        }
    }
    __syncthreads();

    // ---- PV ----
    float acc[8] = {0.f, 0.f, 0.f, 0.f, 0.f, 0.f, 0.f, 0.f};
    #pragma unroll
    for (int ki = 0; ki < KSZ; ++ki) {
        #pragma unroll
        for (int kj = 0; kj < KSZ; ++kj) {
            const float w = lg[ki * 7 + kj];
            const float* vp = &Ks[(nb0 + ki * REG + kj) * KST + q4 * 8];
            const float4 v0 = *reinterpret_cast<const float4*>(vp);
            const float4 v1 = *reinterpret_cast<const float4*>(vp + 4);
            acc[0] = fmaf(w, v0.x, acc[0]);
            acc[1] = fmaf(w, v0.y, acc[1]);
            acc[2] = fmaf(w, v0.z, acc[2]);
            acc[3] = fmaf(w, v0.w, acc[3]);
            acc[4] = fmaf(w, v1.x, acc[4]);
            acc[5] = fmaf(w, v1.y, acc[5]);
            acc[6] = fmaf(w, v1.z, acc[6]);
            acc[7] = fmaf(w, v1.w, acc[7]);
        }
    }

    const float inv = 1.f / ssum;
    float* op = ob + (size_t)tokflat * 256 + head * 32 + q4 * 8;
    float4 o0 = make_float4(acc[0] * inv, acc[1] * inv, acc[2] * inv, acc[3] * inv);
    float4 o1 = make_float4(acc[4] * inv, acc[5] * inv, acc[6] * inv, acc[7] * inv);
    *reinterpret_cast<float4*>(op) = o0;
    *reinterpret_cast<float4*>(op + 4) = o1;
}

// ---------------------------------------------------------------------------
extern "C" void kernel_launch(void* const* d_in, const int* in_sizes, int n_in,
                              void* d_out, int out_size, void* d_ws, size_t ws_size,
                              hipStream_t stream) {
    const float* x_q   = (const float*)d_in[0];
    const float* x_k   = (const float*)d_in[1];
    const float* Wq    = (const float*)d_in[2];
    const float* bq    = (const float*)d_in[3];
    const float* Wkv   = (const float*)d_in[4];
    const float* bkv   = (const float*)d_in[5];
    const float* rpb   = (const float*)d_in[6];
    const float* Wproj = (const float*)d_in[7];
    const float* bproj = (const float*)d_in[8];
    float* out = (float*)d_out;

    const int M = 2 * HS * WS;        // 6272 tokens
    float* qbuf   = (float*)d_ws;                   // M*256 floats
    float* kvbuf  = qbuf + (size_t)M * 256;         // M*512 floats
    float* attbuf = kvbuf + (size_t)M * 512;        // M*256 floats

    const float scale = 0.17677669529663687f;       // 32^-0.5

    dim3 blk(256);
    gemm_bias_kernel<64, 64, 16><<<dim3(256 / 64, M / 64), blk, 0, stream>>>(
        x_q, Wq, bq, qbuf, M, 256, 256, scale);
    gemm_bias_kernel<64, 64, 16><<<dim3(512 / 64, M / 64), blk, 0, stream>>>(
        x_k, Wkv, bkv, kvbuf, M, 512, 256, 1.0f);
    // natten: 2 batches x 8 heads x 7x7 tiles = 784 blocks
    natten_kernel<<<dim3(784), blk, 0, stream>>>(qbuf, kvbuf, rpb, attbuf);
    gemm_bias_kernel<64, 64, 16><<<dim3(256 / 64, M / 64), blk, 0, stream>>>(
        attbuf, Wproj, bproj, out, M, 256, 256, 1.0f);
}

// Round 4
// 66.745 us; speedup vs baseline: 2.6575x; 1.4969x over previous
//
#include <hip/hip_runtime.h>
#include <hip/hip_bf16.h>

#define NHEAD 8
#define KSZ 7
#define HS 56
#define WS 56
#define MTOK (2 * HS * WS)      // 6272 tokens

typedef unsigned short ushortT;
typedef unsigned int uintT;

using bf16x8 = __attribute__((ext_vector_type(8))) short;
using f32x4  = __attribute__((ext_vector_type(4))) float;

// float -> bf16 (round-to-nearest-even), returned as raw ushort bits
static __device__ __forceinline__ ushortT f2bf(float x) {
    uintT u = __float_as_uint(x);
    u += 0x7FFFu + ((u >> 16) & 1u);
    return (ushortT)(u >> 16);
}
static __device__ __forceinline__ float bf2f(ushortT h) {
    return __uint_as_float(((uintT)h) << 16);
}

// ---------------------------------------------------------------------------
// Convert activations fp32 -> (hi, lo) bf16.  x = hi + lo exactly to ~2^-18.
// Handles x_q and x_k in one dispatch. 4 floats / thread.
// ---------------------------------------------------------------------------
__global__ __launch_bounds__(256) void cvt_act_kernel(
    const float* __restrict__ xq, const float* __restrict__ xk,
    ushortT* __restrict__ qhi, ushortT* __restrict__ qlo,
    ushortT* __restrict__ khi, ushortT* __restrict__ klo)
{
    const int NT4 = MTOK * 256 / 4;           // float4s per tensor
    int idx = blockIdx.x * 256 + threadIdx.x; // 0 .. 2*NT4-1
    const float* src = xq; ushortT* dh = qhi; ushortT* dl = qlo;
    int i = idx;
    if (idx >= NT4) { src = xk; dh = khi; dl = klo; i = idx - NT4; }
    float4 v = reinterpret_cast<const float4*>(src)[i];
    const float f[4] = {v.x, v.y, v.z, v.w};
    ushort4 h, l;
    ushortT* hp = &h.x; ushortT* lp = &l.x;
    #pragma unroll
    for (int t = 0; t < 4; ++t) {
        ushortT hb = f2bf(f[t]);
        hp[t] = hb;
        lp[t] = f2bf(f[t] - bf2f(hb));
    }
    reinterpret_cast<ushort4*>(dh)[i] = h;
    reinterpret_cast<ushort4*>(dl)[i] = l;
}

// ---------------------------------------------------------------------------
// Transpose + convert weights: W[K][N] fp32 -> WT_hi/lo[N][K] bf16.
// One fused dispatch covers Wq (64 tiles), Wkv (128), Wproj (64): 256 blocks,
// each transposing a 32x32 tile through LDS.
// ---------------------------------------------------------------------------
__global__ __launch_bounds__(256) void cvt_w_kernel(
    const float* __restrict__ Wq, const float* __restrict__ Wkv,
    const float* __restrict__ Wp,
    ushortT* __restrict__ qThi, ushortT* __restrict__ qTlo,
    ushortT* __restrict__ kvThi, ushortT* __restrict__ kvTlo,
    ushortT* __restrict__ pThi, ushortT* __restrict__ pTlo)
{
    __shared__ float Ts[32][33];
    const int b = blockIdx.x;
    const float* W; ushortT *Th, *Tl; int N, tile;
    if (b < 64)       { W = Wq;  Th = qThi;  Tl = qTlo;  N = 256; tile = b; }
    else if (b < 192) { W = Wkv; Th = kvThi; Tl = kvTlo; N = 512; tile = b - 64; }
    else              { W = Wp;  Th = pThi;  Tl = pTlo;  N = 256; tile = b - 192; }
    const int K = 256;
    const int ntiles_n = N / 32;
    const int k0 = (tile / ntiles_n) * 32;
    const int n0 = (tile % ntiles_n) * 32;

    const int t = threadIdx.x;
    {   // read 32x32 fp32 tile, coalesced along n
        const int kk = t >> 3, nn4 = (t & 7) * 4;
        float4 v = *reinterpret_cast<const float4*>(&W[(size_t)(k0 + kk) * N + n0 + nn4]);
        Ts[kk][nn4 + 0] = v.x; Ts[kk][nn4 + 1] = v.y;
        Ts[kk][nn4 + 2] = v.z; Ts[kk][nn4 + 3] = v.w;
    }
    __syncthreads();
    {   // write transposed, coalesced along k
        const int nn = t >> 3, kk4 = (t & 7) * 4;
        ushort4 h, l;
        ushortT* hp = &h.x; ushortT* lp = &l.x;
        #pragma unroll
        for (int i = 0; i < 4; ++i) {
            float x = Ts[kk4 + i][nn];
            ushortT hb = f2bf(x);
            hp[i] = hb;
            lp[i] = f2bf(x - bf2f(hb));
        }
        const size_t o = (size_t)(n0 + nn) * K + k0 + kk4;
        *reinterpret_cast<ushort4*>(&Th[o]) = h;
        *reinterpret_cast<ushort4*>(&Tl[o]) = l;
    }
}

// ---------------------------------------------------------------------------
// bf16 MFMA GEMM with hi/lo compensation (3 passes, lo*lo dropped):
//   C[M][N] = (A @ B + bias) * scale,  A = Ahi+Alo [M][K],  BT = [N][K] hi/lo
// Block: 64x64 output, 256 thr = 4 waves of 32x32. BK=64.
// LDS rows padded to 72 bf16 (144B): frag reads provably bank-uniform.
// mfma_f32_16x16x32_bf16; A frag: row=lane&15, k=(lane>>4)*8+i (B symmetric);
// D: col=lane&15, row=(lane>>4)*4+reg  [HW-verified layout].
// ---------------------------------------------------------------------------
#define LSTR 72   // LDS row stride in bf16 elements

__global__ __launch_bounds__(256) void gemm_mfma3_kernel(
    const ushortT* __restrict__ Ahi, const ushortT* __restrict__ Alo,
    const ushortT* __restrict__ BThi, const ushortT* __restrict__ BTlo,
    const float* __restrict__ bias, float* __restrict__ C,
    int M, int N, int K, float scale)
{
    __shared__ ushortT Ah[64 * LSTR];
    __shared__ ushortT Al[64 * LSTR];
    __shared__ ushortT Bh[64 * LSTR];
    __shared__ ushortT Bl[64 * LSTR];

    const int tid  = threadIdx.x;
    const int lane = tid & 63;
    const int w    = tid >> 6;          // wave 0..3
    const int wm   = w >> 1;            // wave tile row (0..1)
    const int wn   = w & 1;             // wave tile col (0..1)
    const int l16  = lane & 15;
    const int lhi  = lane >> 4;

    const int m0 = blockIdx.y * 64;
    const int n0 = blockIdx.x * 64;

    // staging: thread copies 32B (16 bf16) per buffer; row = tid>>2
    const int sr  = tid >> 2;
    const int sc  = (tid & 3) * 16;     // element offset within 64-elem row

    f32x4 acc[2][2];
    #pragma unroll
    for (int mi = 0; mi < 2; ++mi)
        #pragma unroll
        for (int ni = 0; ni < 2; ++ni) acc[mi][ni] = (f32x4){0.f, 0.f, 0.f, 0.f};

    for (int kt = 0; kt < K; kt += 64) {
        __syncthreads();   // previous iteration's reads complete
        {
            const size_t ga = (size_t)(m0 + sr) * K + kt + sc;
            const size_t gb = (size_t)(n0 + sr) * K + kt + sc;
            const int ld = sr * LSTR + sc;
            *reinterpret_cast<uint4*>(&Ah[ld])     = *reinterpret_cast<const uint4*>(&Ahi[ga]);
            *reinterpret_cast<uint4*>(&Ah[ld + 8]) = *reinterpret_cast<const uint4*>(&Ahi[ga + 8]);
            *reinterpret_cast<uint4*>(&Al[ld])     = *reinterpret_cast<const uint4*>(&Alo[ga]);
            *reinterpret_cast<uint4*>(&Al[ld + 8]) = *reinterpret_cast<const uint4*>(&Alo[ga + 8]);
            *reinterpret_cast<uint4*>(&Bh[ld])     = *reinterpret_cast<const uint4*>(&BThi[gb]);
            *reinterpret_cast<uint4*>(&Bh[ld + 8]) = *reinterpret_cast<const uint4*>(&BThi[gb + 8]);
            *reinterpret_cast<uint4*>(&Bl[ld])     = *reinterpret_cast<const uint4*>(&BTlo[gb]);
            *reinterpret_cast<uint4*>(&Bl[ld + 8]) = *reinterpret_cast<const uint4*>(&BTlo[gb + 8]);
        }
        __syncthreads();

        #pragma unroll
        for (int ks = 0; ks < 2; ++ks) {
            bf16x8 afh[2], afl[2], bfh[2], bfl[2];
            #pragma unroll
            for (int mi = 0; mi < 2; ++mi) {
                const int ao = (wm * 32 + mi * 16 + l16) * LSTR + ks * 32 + lhi * 8;
                afh[mi] = *reinterpret_cast<const bf16x8*>(&Ah[ao]);
                afl[mi] = *reinterpret_cast<const bf16x8*>(&Al[ao]);
            }
            #pragma unroll
            for (int ni = 0; ni < 2; ++ni) {
                const int bo = (wn * 32 + ni * 16 + l16) * LSTR + ks * 32 + lhi * 8;
                bfh[ni] = *reinterpret_cast<const bf16x8*>(&Bh[bo]);
                bfl[ni] = *reinterpret_cast<const bf16x8*>(&Bl[bo]);
            }
            #pragma unroll
            for (int mi = 0; mi < 2; ++mi)
                #pragma unroll
                for (int ni = 0; ni < 2; ++ni) {
                    acc[mi][ni] = __builtin_amdgcn_mfma_f32_16x16x32_bf16(
                        afh[mi], bfh[ni], acc[mi][ni], 0, 0, 0);
                    acc[mi][ni] = __builtin_amdgcn_mfma_f32_16x16x32_bf16(
                        afh[mi], bfl[ni], acc[mi][ni], 0, 0, 0);
                    acc[mi][ni] = __builtin_amdgcn_mfma_f32_16x16x32_bf16(
                        afl[mi], bfh[ni], acc[mi][ni], 0, 0, 0);
                }
        }
    }

    // epilogue: D col = lane&15, row = (lane>>4)*4 + reg
    #pragma unroll
    for (int mi = 0; mi < 2; ++mi)
        #pragma unroll
        for (int ni = 0; ni < 2; ++ni) {
            const int row = m0 + wm * 32 + mi * 16 + lhi * 4;
            const int col = n0 + wn * 32 + ni * 16 + l16;
            const float bv = bias[col];
            #pragma unroll
            for (int rg = 0; rg < 4; ++rg)
                C[(size_t)(row + rg) * N + col] = (acc[mi][ni][rg] + bv) * scale;
        }
}

// ---------------------------------------------------------------------------
// LDS-tiled neighborhood attention (as R2), now emitting hi/lo bf16 output
// for the MFMA projection GEMM.
// ---------------------------------------------------------------------------
#define REG 14
#define NREG (REG*REG)
#define KST 36

__global__ __launch_bounds__(256) void natten_kernel(
    const float* __restrict__ qb, const float* __restrict__ kvb,
    const float* __restrict__ rpb,
    ushortT* __restrict__ ohi, ushortT* __restrict__ olo)
{
    __shared__ float Ks[NREG * KST];
    __shared__ float Rp[169];

    const int tid = threadIdx.x;
    const int bid = blockIdx.x;             // 784 blocks
    const int head = bid & 7;
    const int idx  = bid >> 3;
    const int b    = idx / 49;
    const int t49  = idx % 49;
    const int ti0  = (t49 / 7) * 8;
    const int tj0  = (t49 % 7) * 8;

    int gr0 = ti0 - 3; gr0 = gr0 < 0 ? 0 : gr0; gr0 = gr0 > HS - REG ? HS - REG : gr0;
    int gc0 = tj0 - 3; gc0 = gc0 < 0 ? 0 : gc0; gc0 = gc0 > WS - REG ? WS - REG : gc0;

    const float* kvb_head = kvb + (size_t)b * 3136 * 512 + head * 32;

    #pragma unroll
    for (int rt0 = 0; rt0 < NREG; rt0 += 32) {
        const int rt = rt0 + (tid >> 3);
        if (rt < NREG) {
            const int r = rt / REG, c = rt % REG;
            const int g = (gr0 + r) * WS + (gc0 + c);
            const float4 v = *reinterpret_cast<const float4*>(
                kvb_head + (size_t)g * 512 + (tid & 7) * 4);
            *reinterpret_cast<float4*>(&Ks[rt * KST + (tid & 7) * 4]) = v;
        }
    }
    if (tid < 169) Rp[tid] = rpb[head * 169 + tid];

    const int tokl = tid >> 2;
    const int q4   = tid & 3;
    const int tr = tokl >> 3, tc = tokl & 7;
    const int i = ti0 + tr, j = tj0 + tc;

    int si = i - 3; si = si < 0 ? 0 : si; si = si > HS - KSZ ? HS - KSZ : si;
    int sj = j - 3; sj = sj < 0 ? 0 : sj; sj = sj > WS - KSZ ? WS - KSZ : sj;

    const int nb0 = (si - gr0) * REG + (sj - gc0);
    const int rb0 = (si - i + 6) * 13 + (sj - j + 6);
    const int tokflat = b * 3136 + i * WS + j;

    const float* qp = qb + (size_t)tokflat * 256 + head * 32 + q4 * 8;
    const float4 qv0 = *reinterpret_cast<const float4*>(qp);
    const float4 qv1 = *reinterpret_cast<const float4*>(qp + 4);

    __syncthreads();

    float lg[49];
    #pragma unroll
    for (int ki = 0; ki < KSZ; ++ki) {
        #pragma unroll
        for (int kj = 0; kj < KSZ; ++kj) {
            const float* kp = &Ks[(nb0 + ki * REG + kj) * KST + q4 * 8];
            const float4 k0 = *reinterpret_cast<const float4*>(kp);
            const float4 k1 = *reinterpret_cast<const float4*>(kp + 4);
            float p = qv0.x * k0.x;
            p = fmaf(qv0.y, k0.y, p);
            p = fmaf(qv0.z, k0.z, p);
            p = fmaf(qv0.w, k0.w, p);
            p = fmaf(qv1.x, k1.x, p);
            p = fmaf(qv1.y, k1.y, p);
            p = fmaf(qv1.z, k1.z, p);
            p = fmaf(qv1.w, k1.w, p);
            p += __shfl_xor(p, 1);
            p += __shfl_xor(p, 2);
            lg[ki * 7 + kj] = p + Rp[rb0 + ki * 13 + kj];
        }
    }

    float m = -1e30f;
    #pragma unroll
    for (int l = 0; l < 49; ++l) m = fmaxf(m, lg[l]);
    float ssum = 0.f;
    #pragma unroll
    for (int l = 0; l < 49; ++l) {
        const float e = __expf(lg[l] - m);
        lg[l] = e;
        ssum += e;
    }

    __syncthreads();

    #pragma unroll
    for (int rt0 = 0; rt0 < NREG; rt0 += 32) {
        const int rt = rt0 + (tid >> 3);
        if (rt < NREG) {
            const int r = rt / REG, c = rt % REG;
            const int g = (gr0 + r) * WS + (gc0 + c);
            const float4 v = *reinterpret_cast<const float4*>(
                kvb_head + (size_t)g * 512 + 256 + (tid & 7) * 4);
            *reinterpret_cast<float4*>(&Ks[rt * KST + (tid & 7) * 4]) = v;
        }
    }
    __syncthreads();

    float acc[8] = {0.f, 0.f, 0.f, 0.f, 0.f, 0.f, 0.f, 0.f};
    #pragma unroll
    for (int ki = 0; ki < KSZ; ++ki) {
        #pragma unroll
        for (int kj = 0; kj < KSZ; ++kj) {
            const float w = lg[ki * 7 + kj];
            const float* vp = &Ks[(nb0 + ki * REG + kj) * KST + q4 * 8];
            const float4 v0 = *reinterpret_cast<const float4*>(vp);
            const float4 v1 = *reinterpret_cast<const float4*>(vp + 4);
            acc[0] = fmaf(w, v0.x, acc[0]);
            acc[1] = fmaf(w, v0.y, acc[1]);
            acc[2] = fmaf(w, v0.z, acc[2]);
            acc[3] = fmaf(w, v0.w, acc[3]);
            acc[4] = fmaf(w, v1.x, acc[4]);
            acc[5] = fmaf(w, v1.y, acc[5]);
            acc[6] = fmaf(w, v1.z, acc[6]);
            acc[7] = fmaf(w, v1.w, acc[7]);
        }
    }

    const float inv = 1.f / ssum;
    union { ushortT u[8]; uint4 v; } ph, pl;
    #pragma unroll
    for (int d = 0; d < 8; ++d) {
        const float x = acc[d] * inv;
        const ushortT hb = f2bf(x);
        ph.u[d] = hb;
        pl.u[d] = f2bf(x - bf2f(hb));
    }
    const size_t o = (size_t)tokflat * 256 + head * 32 + q4 * 8;
    *reinterpret_cast<uint4*>(&ohi[o]) = ph.v;
    *reinterpret_cast<uint4*>(&olo[o]) = pl.v;
}

// ---------------------------------------------------------------------------
extern "C" void kernel_launch(void* const* d_in, const int* in_sizes, int n_in,
                              void* d_out, int out_size, void* d_ws, size_t ws_size,
                              hipStream_t stream) {
    const float* x_q   = (const float*)d_in[0];
    const float* x_k   = (const float*)d_in[1];
    const float* Wq    = (const float*)d_in[2];
    const float* bq    = (const float*)d_in[3];
    const float* Wkv   = (const float*)d_in[4];
    const float* bkv   = (const float*)d_in[5];
    const float* rpb   = (const float*)d_in[6];
    const float* Wproj = (const float*)d_in[7];
    const float* bproj = (const float*)d_in[8];
    float* out = (float*)d_out;

    const int M = MTOK;

    float* qbuf  = (float*)d_ws;                      // M*256 f32
    float* kvbuf = qbuf + (size_t)M * 256;            // M*512 f32
    ushortT* u   = (ushortT*)(kvbuf + (size_t)M * 512);
    ushortT* xq_hi = u;                 u += (size_t)M * 256;
    ushortT* xq_lo = u;                 u += (size_t)M * 256;
    ushortT* xk_hi = u;                 u += (size_t)M * 256;
    ushortT* xk_lo = u;                 u += (size_t)M * 256;
    ushortT* at_hi = u;                 u += (size_t)M * 256;
    ushortT* at_lo = u;                 u += (size_t)M * 256;
    ushortT* WqThi = u;                 u += 256 * 256;
    ushortT* WqTlo = u;                 u += 256 * 256;
    ushortT* WkvThi = u;                u += 512 * 256;
    ushortT* WkvTlo = u;                u += 512 * 256;
    ushortT* WpThi = u;                 u += 256 * 256;
    ushortT* WpTlo = u;                 u += 256 * 256;

    const float scale = 0.17677669529663687f;   // 32^-0.5

    dim3 blk(256);
    cvt_act_kernel<<<dim3(2 * M * 256 / 4 / 256), blk, 0, stream>>>(
        x_q, x_k, xq_hi, xq_lo, xk_hi, xk_lo);
    cvt_w_kernel<<<dim3(256), blk, 0, stream>>>(
        Wq, Wkv, Wproj, WqThi, WqTlo, WkvThi, WkvTlo, WpThi, WpTlo);

    // q = (x_q @ Wq + bq) * scale
    gemm_mfma3_kernel<<<dim3(256 / 64, M / 64), blk, 0, stream>>>(
        xq_hi, xq_lo, WqThi, WqTlo, bq, qbuf, M, 256, 256, scale);
    // kv = x_k @ Wkv + bkv
    gemm_mfma3_kernel<<<dim3(512 / 64, M / 64), blk, 0, stream>>>(
        xk_hi, xk_lo, WkvThi, WkvTlo, bkv, kvbuf, M, 512, 256, 1.0f);
    // neighborhood attention -> hi/lo bf16
    natten_kernel<<<dim3(784), blk, 0, stream>>>(qbuf, kvbuf, rpb, at_hi, at_lo);
    // out = att @ Wproj + bproj
    gemm_mfma3_kernel<<<dim3(256 / 64, M / 64), blk, 0, stream>>>(
        at_hi, at_lo, WpThi, WpTlo, bproj, out, M, 256, 256, 1.0f);
}

// Round 5
// 57.598 us; speedup vs baseline: 3.0796x; 1.1588x over previous
//
#include <hip/hip_runtime.h>
#include <hip/hip_bf16.h>

#define NHEAD 8
#define KSZ 7
#define HS 56
#define WS 56
#define MTOK (2 * HS * WS)      // 6272 tokens

typedef unsigned short u16;
typedef unsigned int u32;

using bf16x8 = __attribute__((ext_vector_type(8))) short;
using f32x4  = __attribute__((ext_vector_type(4))) float;

static __device__ __forceinline__ u16 f2bf(float x) {
    u32 u = __float_as_uint(x);
    u += 0x7FFFu + ((u >> 16) & 1u);
    return (u16)(u >> 16);
}
static __device__ __forceinline__ float bf2f(u16 h) {
    return __uint_as_float(((u32)h) << 16);
}

// global -> LDS direct copy, 16B per lane. LDS dest is wave-uniform base
// + lane*16 (HW rule); global src is per-lane.
static __device__ __forceinline__ void gload16(const void* g, void* l) {
    __builtin_amdgcn_global_load_lds(
        (const __attribute__((address_space(1))) u32*)g,
        (__attribute__((address_space(3))) u32*)l, 16, 0, 0);
}

// ---------------------------------------------------------------------------
// Weights: W[K][N] fp32 -> WT_hi/lo[N][K] bf16, CHUNK-SWIZZLED:
// within each 64-elem k-segment, 16B chunk index c (0..7) is stored at
// c ^ (n&7).  The GEMM then global_load_lds's rows linearly and applies the
// same XOR on its ds_read addresses -> bank-conflict-free, no padding.
// 256 blocks: Wq (64 tiles) -> WTall rows 0..255, Wkv (128) -> rows 256..767,
// Wproj (64) -> WpT.
// ---------------------------------------------------------------------------
__global__ __launch_bounds__(256) void cvt_w_kernel(
    const float* __restrict__ Wq, const float* __restrict__ Wkv,
    const float* __restrict__ Wp,
    u16* __restrict__ WTall_h, u16* __restrict__ WTall_l,
    u16* __restrict__ WpT_h, u16* __restrict__ WpT_l)
{
    __shared__ float Ts[32][33];
    const int b = blockIdx.x;
    const float* W; u16 *Th, *Tl; int N, tile;
    if (b < 64)       { W = Wq;  Th = WTall_h;             Tl = WTall_l;             N = 256; tile = b; }
    else if (b < 192) { W = Wkv; Th = WTall_h + 256 * 256; Tl = WTall_l + 256 * 256; N = 512; tile = b - 64; }
    else              { W = Wp;  Th = WpT_h;               Tl = WpT_l;               N = 256; tile = b - 192; }
    const int ntiles_n = N / 32;
    const int k0 = (tile / ntiles_n) * 32;
    const int n0 = (tile % ntiles_n) * 32;

    const int t = threadIdx.x;
    {   // read 32x32 fp32 tile, coalesced along n
        const int kk = t >> 3, nn4 = (t & 7) * 4;
        float4 v = *reinterpret_cast<const float4*>(&W[(size_t)(k0 + kk) * N + n0 + nn4]);
        Ts[kk][nn4 + 0] = v.x; Ts[kk][nn4 + 1] = v.y;
        Ts[kk][nn4 + 2] = v.z; Ts[kk][nn4 + 3] = v.w;
    }
    __syncthreads();
    {   // write transposed + swizzled
        const int nn = t >> 3, kk4 = (t & 7) * 4;
        const int n = n0 + nn;
        ushort4 h, l;
        u16* hp = &h.x; u16* lp = &l.x;
        #pragma unroll
        for (int i = 0; i < 4; ++i) {
            float x = Ts[kk4 + i][nn];
            u16 hb = f2bf(x);
            hp[i] = hb;
            lp[i] = f2bf(x - bf2f(hb));
        }
        const int kg = k0 + kk4;
        const int kphys = (kg & ~63) | ((((kg >> 3) & 7) ^ (n & 7)) << 3) | (kg & 7);
        const size_t o = (size_t)n * 256 + kphys;
        *reinterpret_cast<ushort4*>(&Th[o]) = h;
        *reinterpret_cast<ushort4*>(&Tl[o]) = l;
    }
}

// ---------------------------------------------------------------------------
// bf16 MFMA GEMM, 3-pass hi/lo compensation. 64M x 128N x 64K tile, 4 waves.
// QKV=true : A = fp32 (x_q for n0<256 else x_k), converted hi/lo in-reg
//            during staging; outputs qbuf (scaled, +bq) / kvbuf (+bkv).
// QKV=false: A = pre-swizzled bf16 hi/lo (natten out), staged via
//            global_load_lds; output = d_out (+bproj).
// B always staged via global_load_lds from pre-swizzled WT.
// All LDS tiles: rows of 64 bf16 (128B), chunk-XOR-swizzled by (row&7).
// ---------------------------------------------------------------------------
template<bool QKV>
__global__ __launch_bounds__(256) void gemm_mfma_kernel(
    const float* __restrict__ Aq, const float* __restrict__ Akv,
    const u16* __restrict__ Ah, const u16* __restrict__ Al,
    const u16* __restrict__ Wh, const u16* __restrict__ Wl,
    const float* __restrict__ biasq, const float* __restrict__ biaskv,
    float* __restrict__ outq, float* __restrict__ outkv, float scale)
{
    __shared__ __align__(16) u16 AhS[64 * 64];
    __shared__ __align__(16) u16 AlS[64 * 64];
    __shared__ __align__(16) u16 BhS[128 * 64];
    __shared__ __align__(16) u16 BlS[128 * 64];

    const int tid  = threadIdx.x;
    const int lane = tid & 63;
    const int w    = tid >> 6;          // wave 0..3 -> n-range w*32
    const int l16  = lane & 15;
    const int lhi  = lane >> 4;

    const int n0 = blockIdx.x * 128;    // combined col space (0..767 qkv, 0..255 proj)
    const int m0 = blockIdx.y * 64;

    const float* A32 = nullptr;
    if (QKV) A32 = (n0 < 256) ? Aq : Akv;

    // A fp32 staging coords (QKV)
    const int arow = tid >> 2;          // 0..63
    const int akc  = (tid & 3) * 16;    // k element offset
    const int aswz = arow & 7;

    f32x4 acc[4][2];
    #pragma unroll
    for (int mi = 0; mi < 4; ++mi)
        #pragma unroll
        for (int ni = 0; ni < 2; ++ni) acc[mi][ni] = (f32x4){0.f, 0.f, 0.f, 0.f};

    for (int kt = 0; kt < 256; kt += 64) {
        __syncthreads();   // previous iteration's frag reads complete

        // ---- B stage: 128 rows x 64 k, hi+lo, via global_load_lds ----
        #pragma unroll
        for (int i = 0; i < 4; ++i) {
            const int rbase = w * 32 + i * 8;
            const size_t src = (size_t)(n0 + rbase + (lane >> 3)) * 256 + kt + (lane & 7) * 8;
            gload16(Wh + src, &BhS[rbase * 64]);
            gload16(Wl + src, &BlS[rbase * 64]);
        }

        // ---- A stage ----
        if (QKV) {
            const float* ap = &A32[(size_t)(m0 + arow) * 256 + kt + akc];
            float f[16];
            #pragma unroll
            for (int v = 0; v < 4; ++v) {
                float4 t = *reinterpret_cast<const float4*>(ap + v * 4);
                f[v * 4 + 0] = t.x; f[v * 4 + 1] = t.y;
                f[v * 4 + 2] = t.z; f[v * 4 + 3] = t.w;
            }
            union { u16 u[8]; uint4 v; } h0, h1, l0, l1;
            #pragma unroll
            for (int e = 0; e < 8; ++e) {
                u16 hb = f2bf(f[e]);      h0.u[e] = hb; l0.u[e] = f2bf(f[e] - bf2f(hb));
                u16 hb2 = f2bf(f[8 + e]); h1.u[e] = hb2; l1.u[e] = f2bf(f[8 + e] - bf2f(hb2));
            }
            const int c0 = (tid & 3) * 2;
            const int o0 = arow * 64 + ((c0 ^ aswz) << 3);
            const int o1 = arow * 64 + (((c0 + 1) ^ aswz) << 3);
            *reinterpret_cast<uint4*>(&AhS[o0]) = h0.v;
            *reinterpret_cast<uint4*>(&AhS[o1]) = h1.v;
            *reinterpret_cast<uint4*>(&AlS[o0]) = l0.v;
            *reinterpret_cast<uint4*>(&AlS[o1]) = l1.v;
        } else {
            #pragma unroll
            for (int i = 0; i < 2; ++i) {
                const int rbase = w * 16 + i * 8;
                const size_t src = (size_t)(m0 + rbase + (lane >> 3)) * 256 + kt + (lane & 7) * 8;
                gload16(Ah + src, &AhS[rbase * 64]);
                gload16(Al + src, &AlS[rbase * 64]);
            }
        }

        __syncthreads();

        // ---- MFMA ----
        #pragma unroll
        for (int ks = 0; ks < 2; ++ks) {
            const int cph = ((ks * 4 + lhi) ^ (l16 & 7)) << 3;   // physical chunk offset (elems)
            bf16x8 ah[4], al[4], bh[2], bl[2];
            #pragma unroll
            for (int mi = 0; mi < 4; ++mi) {
                const int ro = (mi * 16 + l16) * 64 + cph;
                ah[mi] = *reinterpret_cast<const bf16x8*>(&AhS[ro]);
                al[mi] = *reinterpret_cast<const bf16x8*>(&AlS[ro]);
            }
            #pragma unroll
            for (int ni = 0; ni < 2; ++ni) {
                const int ro = (w * 32 + ni * 16 + l16) * 64 + cph;
                bh[ni] = *reinterpret_cast<const bf16x8*>(&BhS[ro]);
                bl[ni] = *reinterpret_cast<const bf16x8*>(&BlS[ro]);
            }
            #pragma unroll
            for (int mi = 0; mi < 4; ++mi)
                #pragma unroll
                for (int ni = 0; ni < 2; ++ni) {
                    acc[mi][ni] = __builtin_amdgcn_mfma_f32_16x16x32_bf16(
                        ah[mi], bh[ni], acc[mi][ni], 0, 0, 0);
                    acc[mi][ni] = __builtin_amdgcn_mfma_f32_16x16x32_bf16(
                        ah[mi], bl[ni], acc[mi][ni], 0, 0, 0);
                    acc[mi][ni] = __builtin_amdgcn_mfma_f32_16x16x32_bf16(
                        al[mi], bh[ni], acc[mi][ni], 0, 0, 0);
                }
        }
    }

    // ---- epilogue: D col = lane&15, row = (lane>>4)*4 + reg ----
    float* op; const float* bs; int ldo, coff; float sc;
    if (!QKV || n0 < 256) { op = outq;  bs = biasq;  ldo = QKV ? 256 : 256; coff = 0;   sc = scale; }
    else                  { op = outkv; bs = biaskv; ldo = 512;             coff = 256; sc = 1.0f;  }

    #pragma unroll
    for (int ni = 0; ni < 2; ++ni) {
        const int col = n0 + w * 32 + ni * 16 + l16;
        const float bv = bs[col - coff];
        #pragma unroll
        for (int mi = 0; mi < 4; ++mi) {
            const int row = m0 + mi * 16 + lhi * 4;
            #pragma unroll
            for (int rg = 0; rg < 4; ++rg)
                op[(size_t)(row + rg) * ldo + (col - coff)] = (acc[mi][ni][rg] + bv) * sc;
        }
    }
}

// ---------------------------------------------------------------------------
// LDS-tiled neighborhood attention (as R2/R3), emitting CHUNK-SWIZZLED hi/lo
// bf16 so the proj GEMM can global_load_lds it directly.
// ---------------------------------------------------------------------------
#define REG 14
#define NREG (REG*REG)
#define KST 36

__global__ __launch_bounds__(256) void natten_kernel(
    const float* __restrict__ qb, const float* __restrict__ kvb,
    const float* __restrict__ rpb,
    u16* __restrict__ ohi, u16* __restrict__ olo)
{
    __shared__ float Ks[NREG * KST];
    __shared__ float Rp[169];

    const int tid = threadIdx.x;
    const int bid = blockIdx.x;             // 784 blocks
    const int head = bid & 7;
    const int idx  = bid >> 3;
    const int b    = idx / 49;
    const int t49  = idx % 49;
    const int ti0  = (t49 / 7) * 8;
    const int tj0  = (t49 % 7) * 8;

    int gr0 = ti0 - 3; gr0 = gr0 < 0 ? 0 : gr0; gr0 = gr0 > HS - REG ? HS - REG : gr0;
    int gc0 = tj0 - 3; gc0 = gc0 < 0 ? 0 : gc0; gc0 = gc0 > WS - REG ? WS - REG : gc0;

    const float* kvb_head = kvb + (size_t)b * 3136 * 512 + head * 32;

    #pragma unroll
    for (int rt0 = 0; rt0 < NREG; rt0 += 32) {
        const int rt = rt0 + (tid >> 3);
        if (rt < NREG) {
            const int r = rt / REG, c = rt % REG;
            const int g = (gr0 + r) * WS + (gc0 + c);
            const float4 v = *reinterpret_cast<const float4*>(
                kvb_head + (size_t)g * 512 + (tid & 7) * 4);
            *reinterpret_cast<float4*>(&Ks[rt * KST + (tid & 7) * 4]) = v;
        }
    }
    if (tid < 169) Rp[tid] = rpb[head * 169 + tid];

    const int tokl = tid >> 2;
    const int q4   = tid & 3;
    const int tr = tokl >> 3, tc = tokl & 7;
    const int i = ti0 + tr, j = tj0 + tc;

    int si = i - 3; si = si < 0 ? 0 : si; si = si > HS - KSZ ? HS - KSZ : si;
    int sj = j - 3; sj = sj < 0 ? 0 : sj; sj = sj > WS - KSZ ? WS - KSZ : sj;

    const int nb0 = (si - gr0) * REG + (sj - gc0);
    const int rb0 = (si - i + 6) * 13 + (sj - j + 6);
    const int tokflat = b * 3136 + i * WS + j;

    const float* qp = qb + (size_t)tokflat * 256 + head * 32 + q4 * 8;
    const float4 qv0 = *reinterpret_cast<const float4*>(qp);
    const float4 qv1 = *reinterpret_cast<const float4*>(qp + 4);

    __syncthreads();

    float lg[49];
    #pragma unroll
    for (int ki = 0; ki < KSZ; ++ki) {
        #pragma unroll
        for (int kj = 0; kj < KSZ; ++kj) {
            const float* kp = &Ks[(nb0 + ki * REG + kj) * KST + q4 * 8];
            const float4 k0 = *reinterpret_cast<const float4*>(kp);
            const float4 k1 = *reinterpret_cast<const float4*>(kp + 4);
            float p = qv0.x * k0.x;
            p = fmaf(qv0.y, k0.y, p);
            p = fmaf(qv0.z, k0.z, p);
            p = fmaf(qv0.w, k0.w, p);
            p = fmaf(qv1.x, k1.x, p);
            p = fmaf(qv1.y, k1.y, p);
            p = fmaf(qv1.z, k1.z, p);
            p = fmaf(qv1.w, k1.w, p);
            p += __shfl_xor(p, 1);
            p += __shfl_xor(p, 2);
            lg[ki * 7 + kj] = p + Rp[rb0 + ki * 13 + kj];
        }
    }

    float m = -1e30f;
    #pragma unroll
    for (int l = 0; l < 49; ++l) m = fmaxf(m, lg[l]);
    float ssum = 0.f;
    #pragma unroll
    for (int l = 0; l < 49; ++l) {
        const float e = __expf(lg[l] - m);
        lg[l] = e;
        ssum += e;
    }

    __syncthreads();

    #pragma unroll
    for (int rt0 = 0; rt0 < NREG; rt0 += 32) {
        const int rt = rt0 + (tid >> 3);
        if (rt < NREG) {
            const int r = rt / REG, c = rt % REG;
            const int g = (gr0 + r) * WS + (gc0 + c);
            const float4 v = *reinterpret_cast<const float4*>(
                kvb_head + (size_t)g * 512 + 256 + (tid & 7) * 4);
            *reinterpret_cast<float4*>(&Ks[rt * KST + (tid & 7) * 4]) = v;
        }
    }
    __syncthreads();

    float acc[8] = {0.f, 0.f, 0.f, 0.f, 0.f, 0.f, 0.f, 0.f};
    #pragma unroll
    for (int ki = 0; ki < KSZ; ++ki) {
        #pragma unroll
        for (int kj = 0; kj < KSZ; ++kj) {
            const float w = lg[ki * 7 + kj];
            const float* vp = &Ks[(nb0 + ki * REG + kj) * KST + q4 * 8];
            const float4 v0 = *reinterpret_cast<const float4*>(vp);
            const float4 v1 = *reinterpret_cast<const float4*>(vp + 4);
            acc[0] = fmaf(w, v0.x, acc[0]);
            acc[1] = fmaf(w, v0.y, acc[1]);
            acc[2] = fmaf(w, v0.z, acc[2]);
            acc[3] = fmaf(w, v0.w, acc[3]);
            acc[4] = fmaf(w, v1.x, acc[4]);
            acc[5] = fmaf(w, v1.y, acc[5]);
            acc[6] = fmaf(w, v1.z, acc[6]);
            acc[7] = fmaf(w, v1.w, acc[7]);
        }
    }

    const float inv = 1.f / ssum;
    union { u16 u[8]; uint4 v; } ph, pl;
    #pragma unroll
    for (int d = 0; d < 8; ++d) {
        const float x = acc[d] * inv;
        const u16 hb = f2bf(x);
        ph.u[d] = hb;
        pl.u[d] = f2bf(x - bf2f(hb));
    }
    // chunk-swizzled store: k = head*32 + q4*8 -> chunk = head*4+q4
    const int chunk = head * 4 + q4;
    const int seg = chunk >> 3, cin = chunk & 7;
    const int cphys = cin ^ (tokflat & 7);
    const size_t o = (size_t)tokflat * 256 + seg * 64 + cphys * 8;
    *reinterpret_cast<uint4*>(&ohi[o]) = ph.v;
    *reinterpret_cast<uint4*>(&olo[o]) = pl.v;
}

// ---------------------------------------------------------------------------
extern "C" void kernel_launch(void* const* d_in, const int* in_sizes, int n_in,
                              void* d_out, int out_size, void* d_ws, size_t ws_size,
                              hipStream_t stream) {
    const float* x_q   = (const float*)d_in[0];
    const float* x_k   = (const float*)d_in[1];
    const float* Wq    = (const float*)d_in[2];
    const float* bq    = (const float*)d_in[3];
    const float* Wkv   = (const float*)d_in[4];
    const float* bkv   = (const float*)d_in[5];
    const float* rpb   = (const float*)d_in[6];
    const float* Wproj = (const float*)d_in[7];
    const float* bproj = (const float*)d_in[8];
    float* out = (float*)d_out;

    const int M = MTOK;

    float* qbuf  = (float*)d_ws;                      // M*256 f32
    float* kvbuf = qbuf + (size_t)M * 256;            // M*512 f32
    u16* at_hi   = (u16*)(kvbuf + (size_t)M * 512);   // M*256 bf16 (swizzled)
    u16* at_lo   = at_hi + (size_t)M * 256;
    u16* WTall_h = at_lo + (size_t)M * 256;           // 768*256
    u16* WTall_l = WTall_h + 768 * 256;
    u16* WpT_h   = WTall_l + 768 * 256;               // 256*256
    u16* WpT_l   = WpT_h + 256 * 256;

    const float scale = 0.17677669529663687f;   // 32^-0.5

    dim3 blk(256);
    cvt_w_kernel<<<dim3(256), blk, 0, stream>>>(
        Wq, Wkv, Wproj, WTall_h, WTall_l, WpT_h, WpT_l);

    // fused q + kv projection: cols 0..255 = q (A=x_q), 256..767 = kv (A=x_k)
    gemm_mfma_kernel<true><<<dim3(6, M / 64), blk, 0, stream>>>(
        x_q, x_k, nullptr, nullptr, WTall_h, WTall_l,
        bq, bkv, qbuf, kvbuf, scale);

    // neighborhood attention -> swizzled hi/lo bf16
    natten_kernel<<<dim3(784), blk, 0, stream>>>(qbuf, kvbuf, rpb, at_hi, at_lo);

    // out = att @ Wproj + bproj
    gemm_mfma_kernel<false><<<dim3(2, M / 64), blk, 0, stream>>>(
        nullptr, nullptr, at_hi, at_lo, WpT_h, WpT_l,
        bproj, nullptr, out, nullptr, 1.0f);
}